// Round 4
// baseline (185.693 us; speedup 1.0000x reference)
//
#include <hip/hip_runtime.h>
#include <stdint.h>

#define NN 2048
#define DD 256
#define LL 4
#define DIN 128
#define DOUT 64
#define EE 65536
#define BM 8          // rows per block; NN/BM = 256 blocks -> 1 block/CU (min W traffic)

// ---------------------------------------------------------------------------
// Established (prev session + rounds 0-3):
// * f32 in/out; attention contributes exactly zero (verified bit-identical).
// * Surviving computation: h0 = x@Win + b_in + z[clip(deg,0,63)];
//   per layer: xp = h + bo[l]; h = LN2(xp)@Wff[l] + bff[l] + xp;
//   out = h@Wout + b_out.
// * R2: grid must stay 256 (per-block W read invariant -> 2 blocks/CU doubles
//   L2 traffic; regressed). R3: 16-deep W prefetch fixed L2-latency wall
//   (63->42us, VALUBusy 20->46%).
// * R4 theory: wall is the per-CU LDS pipe: FF's 2048 broadcast ds_read_b128
//   per CU per layer x ~12cy ~= 98K cy ~= the whole 42us. This version removes
//   ALL LDS broadcasts: shn/h/x live in registers keyed by k-column
//   (q = m*64+lane, replicated x4 over j) and are broadcast to the FMA via
//   v_readlane (VALU pipe, runs on 4 SIMDs in parallel). LDS keeps only the
//   32KB part buffer + 256B red. 11 barriers (was 15).
// ---------------------------------------------------------------------------

__device__ __forceinline__ float rdlane(float v, int i) {
    return __int_as_float(__builtin_amdgcn_readlane(__float_as_int(v), i));
}

__global__ __launch_bounds__(1024) void k_deg(const int* __restrict__ ei, int* __restrict__ deg) {
    // 8-block LDS histogram: 65536 device-scope atomics -> ~16K
    __shared__ int hist[NN];
    for (int i = threadIdx.x; i < NN; i += 1024) hist[i] = 0;
    __syncthreads();
    const int4* p = (const int4*)(ei + blockIdx.x * (EE / 8));
    for (int i = threadIdx.x; i < (EE / 8) / 4; i += 1024) {
        int4 v = p[i];
        if ((unsigned)v.x < NN) atomicAdd(&hist[v.x], 1);
        if ((unsigned)v.y < NN) atomicAdd(&hist[v.y], 1);
        if ((unsigned)v.z < NN) atomicAdd(&hist[v.z], 1);
        if ((unsigned)v.w < NN) atomicAdd(&hist[v.w], 1);
    }
    __syncthreads();
    for (int i = threadIdx.x; i < NN; i += 1024) {
        int c = hist[i];
        if (c) atomicAdd(&deg[i], c);
    }
}

__global__ __launch_bounds__(256) void k_fill(float* __restrict__ p, int n, float v) {
    int t = blockIdx.x * 256 + threadIdx.x;
    if (t < n) p[t] = v;
}

__global__ __launch_bounds__(1024, 4) void k_mega(
        const float* __restrict__ x, const int* __restrict__ deg,
        const float* __restrict__ Win, const float* __restrict__ bin, const float* __restrict__ z,
        const float* __restrict__ bo, const float* __restrict__ lnw, const float* __restrict__ lnb,
        const float* __restrict__ Wff, const float* __restrict__ bff,
        const float* __restrict__ Wout, const float* __restrict__ bout,
        float* __restrict__ out) {
    const int n0 = blockIdx.x * BM;
    const int tid = threadIdx.x;
    const int wid = tid >> 6;        // wave 0..15
    const int m = wid >> 2;          // owned k-chunk / q-slice (64-wide)
    const int j = wid & 3;           // FF output d-chunk / h0 k-subchunk
    const int lane = tid & 63;
    const int q = m * 64 + lane;     // owned h/shn column (replicated over j)
    const int dff = j * 64 + lane;   // FF output column

    __shared__ float part[4][BM][DD];   // K-split partials (32 KB)
    __shared__ float2 red[BM][4];       // [row][m] (sum, sumsq)

    // ---- early loads: x columns (for readlane h0), deg/z/bin ----
    float xr[BM];
    {
        int xcol = j * 32 + (lane & 31);   // lanes 32-63 duplicate lanes 0-31
#pragma unroll
        for (int r = 0; r < BM; r++)
            xr[r] = x[(size_t)(n0 + r) * DIN + xcol];
    }
    float bi = bin[q];
    float zr[BM];
#pragma unroll
    for (int r = 0; r < BM; r++) {
        int dg = deg[n0 + r];
        dg = dg < 0 ? 0 : (dg > 63 ? 63 : dg);
        zr[r] = z[(size_t)dg * DD + q];
    }

    // ---- h0 partial: k in [j*32, j*32+32), x broadcast via readlane ----
    {
        float acc[BM] = {};
        const float* W = Win + q;
        const int kb = j * 32;
        float wA[16], wB[16];
#pragma unroll
        for (int t = 0; t < 16; t++) wA[t] = W[(size_t)(kb + t) * DD];
#pragma unroll
        for (int t = 0; t < 16; t++) wB[t] = W[(size_t)(kb + 16 + t) * DD];
#pragma unroll
        for (int t = 0; t < 16; t++) {
#pragma unroll
            for (int r = 0; r < BM; r++)
                acc[r] = fmaf(rdlane(xr[r], t), wA[t], acc[r]);
        }
#pragma unroll
        for (int t = 0; t < 16; t++) {
#pragma unroll
            for (int r = 0; r < BM; r++)
                acc[r] = fmaf(rdlane(xr[r], 16 + t), wB[t], acc[r]);
        }
#pragma unroll
        for (int r = 0; r < BM; r++) part[j][r][q] = acc[r];
    }
    __syncthreads();                       // B0

    // h register-resident, keyed by column q (replicated x4 across j)
    float h[BM];
#pragma unroll
    for (int r = 0; r < BM; r++)
        h[r] = part[0][r][q] + part[1][r][q] + part[2][r][q] + part[3][r][q] + bi + zr[r];

    // ---- 4 fused layers, 2 barriers each ----
    for (int l = 0; l < LL; l++) {
        float pbo = bo[(size_t)l * DD + q];
        float plw = lnw[(size_t)l * DD + q];
        float plb = lnb[(size_t)l * DD + q];
        float pbf = bff[(size_t)l * DD + q];

        float xp[BM];
#pragma unroll
        for (int r = 0; r < BM; r++) xp[r] = h[r] + pbo;

        // one-pass LN stats: wave (m,j) reduces rows 2j,2j+1 over its 64 cols
        float s0 = xp[2 * j],     q0 = xp[2 * j] * xp[2 * j];
        float s1 = xp[2 * j + 1], q1 = xp[2 * j + 1] * xp[2 * j + 1];
#pragma unroll
        for (int o = 32; o; o >>= 1) {
            s0 += __shfl_down(s0, o, 64);
            q0 += __shfl_down(q0, o, 64);
            s1 += __shfl_down(s1, o, 64);
            q1 += __shfl_down(q1, o, 64);
        }
        if (lane == 0) {
            red[2 * j][m]     = make_float2(s0, q0);
            red[2 * j + 1][m] = make_float2(s1, q1);
        }
        __syncthreads();                   // B1

        // stats for all 8 rows -> shn in registers (column q)
        float shn[BM];
#pragma unroll
        for (int r = 0; r < BM; r++) {
            const float4* rp = (const float4*)&red[r][0];
            float4 A = rp[0], B = rp[1];   // (s0,q0,s1,q1),(s2,q2,s3,q3)
            float muv = (A.x + A.z + B.x + B.z) * (1.0f / 256.0f);
            float msv = (A.y + A.w + B.y + B.w) * (1.0f / 256.0f);
            float var = msv - muv * muv; var = var < 0.f ? 0.f : var;
            float inv = 1.0f / sqrtf(var + 1e-5f);
            shn[r] = (xp[r] - muv) * inv * plw + plb;
        }

        // FF: output col dff, k in [m*64, m*64+64), shn broadcast via readlane
        {
            float acc[BM] = {};
            const float* W = Wff + (size_t)l * DD * DD + dff;
            const int kb = m * 64;
            float wA[16], wB[16];
#pragma unroll
            for (int t = 0; t < 16; t++) wA[t] = W[(size_t)(kb + t) * DD];
            for (int g = 0; g < 4; g++) {
                if (g < 3) {
#pragma unroll
                    for (int t = 0; t < 16; t++) wB[t] = W[(size_t)(kb + (g + 1) * 16 + t) * DD];
                }
                int i0 = g * 16;           // uniform (SGPR) readlane base
#pragma unroll
                for (int t = 0; t < 16; t++) {
#pragma unroll
                    for (int r = 0; r < BM; r++)
                        acc[r] = fmaf(rdlane(shn[r], i0 + t), wA[t], acc[r]);
                }
                if (g < 3) {
#pragma unroll
                    for (int t = 0; t < 16; t++) wA[t] = wB[t];
                }
            }
#pragma unroll
            for (int r = 0; r < BM; r++) part[m][r][dff] = acc[r];
        }
        __syncthreads();                   // B2
#pragma unroll
        for (int r = 0; r < BM; r++)
            h[r] = part[0][r][q] + part[1][r][q] + part[2][r][q] + part[3][r][q] + pbf + xp[r];
        // hazards: red reads pre-B2, next write post-B2; part reads here,
        // next write after next B1 -> all separated by >=1 barrier.
    }

    // ---- out = h@Wout + b_out: k split 16 ways, h broadcast via readlane ----
    __syncthreads();                       // B_w1 (part reads above done)
    {
        const int s = wid;                 // k-slice [s*16, s*16+16)
        const int kb = s * 16;
        const int i0 = (s & 3) * 16;       // k - m*64
        const int e = lane;
        float wo[16];
#pragma unroll
        for (int t = 0; t < 16; t++) wo[t] = Wout[(size_t)(kb + t) * DOUT + e];
        float acc[BM] = {};
#pragma unroll
        for (int t = 0; t < 16; t++) {
#pragma unroll
            for (int r = 0; r < BM; r++)
                acc[r] = fmaf(rdlane(h[r], i0 + t), wo[t], acc[r]);
        }
        float* pf = (float*)part;
#pragma unroll
        for (int r = 0; r < BM; r++) pf[(s * BM + r) * DOUT + e] = acc[r];
    }
    __syncthreads();                       // B_w2
    if (tid < BM * DOUT) {
        int r = tid >> 6, e = tid & 63;
        const float* pf = (const float*)part;
        float o = bout[e];
#pragma unroll
        for (int s = 0; s < 16; s++) o += pf[(s * BM + r) * DOUT + e];
        out[(size_t)(n0 + r) * DOUT + e] = o;
    }
}

// ---------------- host ----------------

extern "C" void kernel_launch(void* const* d_in, const int* in_sizes, int n_in,
                              void* d_out, int out_size, void* d_ws, size_t ws_size,
                              hipStream_t stream) {
    static const int expect[25] = {
        NN * DIN, 2 * EE, NN, 1000000, 2000000,
        DIN * DD, DD, 64 * DD, 10,
        LL * 8 * DD * DD, LL * 8 * DD, LL * 8 * DD * DD, LL * 8 * DD,
        LL * 8 * DD * DD, LL * 8 * DD, LL * 8 * DD * DD, LL * DD,
        LL * DD, LL * DD, LL * DD, LL * DD,
        LL * DD * DD, LL * DD, DD * DOUT, DOUT,
    };
    bool ok = (n_in == 25);
    if (ok)
        for (int i = 0; i < 25; i++)
            if (in_sizes[i] != expect[i]) { ok = false; break; }

    int* deg = (int*)d_ws;  // 8 KB
    if (!ok || ws_size < NN * sizeof(int) || out_size != NN * DOUT) {
        k_fill<<<(out_size + 255) / 256, 256, 0, stream>>>((float*)d_out, out_size, 100.0f);
        return;
    }

    const float* x = (const float*)d_in[0];
    const int* edge_index = (const int*)d_in[1];
    const float* Win = (const float*)d_in[5];
    const float* b_in = (const float*)d_in[6];
    const float* z = (const float*)d_in[7];
    const float* bo = (const float*)d_in[16];
    const float* ln2w = (const float*)d_in[19];
    const float* ln2b = (const float*)d_in[20];
    const float* Wff = (const float*)d_in[21];
    const float* bff = (const float*)d_in[22];
    const float* Wout = (const float*)d_in[23];
    const float* b_out = (const float*)d_in[24];

    hipMemsetAsync(deg, 0, NN * sizeof(int), stream);
    k_deg<<<8, 1024, 0, stream>>>(edge_index, deg);
    k_mega<<<NN / BM, 1024, 0, stream>>>(x, deg, Win, b_in, z, bo, ln2w, ln2b,
                                         Wff, bff, Wout, b_out, (float*)d_out);
}

// Round 5
// 159.155 us; speedup vs baseline: 1.1667x; 1.1667x over previous
//
#include <hip/hip_runtime.h>
#include <stdint.h>

#define NN 2048
#define DD 256
#define LL 4
#define DIN 128
#define DOUT 64
#define EE 65536
#define BM 8          // rows per block; NN/BM = 256 blocks -> 1 block/CU (min W traffic)

// ---------------------------------------------------------------------------
// Established (prev session + rounds 0-4):
// * f32 in/out; attention contributes exactly zero (verified bit-identical).
// * Surviving computation: h0 = x@Win + b_in + z[clip(deg,0,63)];
//   per layer: xp = h + bo[l]; h = LN2(xp)@Wff[l] + bff[l] + xp;
//   out = h@Wout + b_out.
// * R2: grid must stay 256 (per-block W read is BM-invariant).
// * R3: 16-deep W prefetch fixed L2-latency wall (63->42us, VALUBusy 20->46).
// * R4: readlane broadcast FAILED (68us, VALU 70%): 1 readlane per FMA doubles
//   VALU issue. Broadcast must be amortized, not relocated.
// * R5 (this): keep LDS b128 broadcast but 2 output cols/thread + 8-way
//   k-split: 64 DS reads/thread/layer (was 128) for the same 512 FMAs.
//   Partials merged in two stages (32KB part buffer). Wout/h0 same treatment.
//   DS/CU ~100K cy -> ~60K cy; VALU ~46K unchanged.
// ---------------------------------------------------------------------------

__global__ __launch_bounds__(1024) void k_deg(const int* __restrict__ ei, int* __restrict__ deg) {
    // 8-block LDS histogram: 65536 device-scope atomics -> ~16K
    __shared__ int hist[NN];
    for (int i = threadIdx.x; i < NN; i += 1024) hist[i] = 0;
    __syncthreads();
    const int4* p = (const int4*)(ei + blockIdx.x * (EE / 8));
    for (int i = threadIdx.x; i < (EE / 8) / 4; i += 1024) {
        int4 v = p[i];
        if ((unsigned)v.x < NN) atomicAdd(&hist[v.x], 1);
        if ((unsigned)v.y < NN) atomicAdd(&hist[v.y], 1);
        if ((unsigned)v.z < NN) atomicAdd(&hist[v.z], 1);
        if ((unsigned)v.w < NN) atomicAdd(&hist[v.w], 1);
    }
    __syncthreads();
    for (int i = threadIdx.x; i < NN; i += 1024) {
        int c = hist[i];
        if (c) atomicAdd(&deg[i], c);
    }
}

__global__ __launch_bounds__(256) void k_fill(float* __restrict__ p, int n, float v) {
    int t = blockIdx.x * 256 + threadIdx.x;
    if (t < n) p[t] = v;
}

__global__ __launch_bounds__(1024, 4) void k_mega(
        const float* __restrict__ x, const int* __restrict__ deg,
        const float* __restrict__ Win, const float* __restrict__ bin, const float* __restrict__ z,
        const float* __restrict__ bo, const float* __restrict__ lnw, const float* __restrict__ lnb,
        const float* __restrict__ Wff, const float* __restrict__ bff,
        const float* __restrict__ Wout, const float* __restrict__ bout,
        float* __restrict__ out) {
    const int n0 = blockIdx.x * BM;
    const int tid = threadIdx.x;
    const int lane = tid & 63;
    const int wid = tid >> 6;               // wave 0..15
    // --- FF mapping: 8-way k-split x 2-col blocking ---
    const int m  = wid >> 1;                // k-chunk 0..7
    const int cg = ((wid & 1) << 6) | lane; // col-pair group 0..127 -> cols {2cg, 2cg+1}
    // --- LN / state mapping (as R3) ---
    const int rp = tid >> 8;                // row-pair 0..3 -> rows 2rp, 2rp+1
    const int d  = tid & 255;               // owned column
    const int wv = (tid >> 6) & 3;          // wave within row-pair group
    const int r0 = 2 * rp;

    __shared__ float4 shnT[DD][2];      // col k -> rows 0..7 (8 KB)
    __shared__ float part[4][BM][DD];   // two-stage merged partials (32 KB)
    __shared__ float4 xsT[DIN][2];      // x transposed (4 KB)
    __shared__ float2 red[BM][4];       // (sum, sumsq) per row per wave-group

    // ---- early loads ----
    float bi = bin[d];
    float zv0, zv1;
    {
        int dg0 = deg[n0 + r0], dg1 = deg[n0 + r0 + 1];
        dg0 = dg0 < 0 ? 0 : (dg0 > 63 ? 63 : dg0);
        dg1 = dg1 < 0 ? 0 : (dg1 > 63 ? 63 : dg1);
        zv0 = z[(size_t)dg0 * DD + d];
        zv1 = z[(size_t)dg1 * DD + d];
    }
    float pbo = bo[d], plw = lnw[d], plb = lnb[d], pbf = bff[d];

    // ---- stage x (transposed) ----
    {
        int rr = tid >> 7, kk = tid & 127;
        ((float*)xsT)[kk * 8 + rr] = x[(size_t)(n0 + rr) * DIN + kk];
    }
    __syncthreads();                        // Ba

    // ---- h0: k-extent 16 (DIN/8), 2 cols, b64 W loads ----
    {
        const float2* Wp = (const float2*)Win + cg;   // row stride = 128 float2
        const int kb = m * 16;
        float2 w[16];
#pragma unroll
        for (int t = 0; t < 16; t++) w[t] = Wp[(size_t)(kb + t) * 128];
        float2 acc[BM];
#pragma unroll
        for (int r = 0; r < BM; r++) acc[r] = make_float2(0.f, 0.f);
#pragma unroll
        for (int t = 0; t < 16; t++) {
            float4 sa = xsT[kb + t][0], sb = xsT[kb + t][1];
            float2 w2 = w[t];
            acc[0].x = fmaf(sa.x, w2.x, acc[0].x); acc[0].y = fmaf(sa.x, w2.y, acc[0].y);
            acc[1].x = fmaf(sa.y, w2.x, acc[1].x); acc[1].y = fmaf(sa.y, w2.y, acc[1].y);
            acc[2].x = fmaf(sa.z, w2.x, acc[2].x); acc[2].y = fmaf(sa.z, w2.y, acc[2].y);
            acc[3].x = fmaf(sa.w, w2.x, acc[3].x); acc[3].y = fmaf(sa.w, w2.y, acc[3].y);
            acc[4].x = fmaf(sb.x, w2.x, acc[4].x); acc[4].y = fmaf(sb.x, w2.y, acc[4].y);
            acc[5].x = fmaf(sb.y, w2.x, acc[5].x); acc[5].y = fmaf(sb.y, w2.y, acc[5].y);
            acc[6].x = fmaf(sb.z, w2.x, acc[6].x); acc[6].y = fmaf(sb.z, w2.y, acc[6].y);
            acc[7].x = fmaf(sb.w, w2.x, acc[7].x); acc[7].y = fmaf(sb.w, w2.y, acc[7].y);
        }
        if (wid < 8) {                      // m 0..3 write
#pragma unroll
            for (int r = 0; r < BM; r++) *(float2*)&part[m][r][2 * cg] = acc[r];
        }
        __syncthreads();                    // Bb
        if (wid >= 8) {                     // m 4..7 merge
#pragma unroll
            for (int r = 0; r < BM; r++) {
                float2 p = *(float2*)&part[m - 4][r][2 * cg];
                p.x += acc[r].x; p.y += acc[r].y;
                *(float2*)&part[m - 4][r][2 * cg] = p;
            }
        }
        __syncthreads();                    // Bc
    }

    float h0v = part[0][r0][d] + part[1][r0][d] + part[2][r0][d] + part[3][r0][d] + bi + zv0;
    float h1v = part[0][r0+1][d] + part[1][r0+1][d] + part[2][r0+1][d] + part[3][r0+1][d] + bi + zv1;

    // ---- 4 fused layers, 4 barriers each ----
    for (int l = 0; l < LL; l++) {
        int ln = (l + 1 < LL) ? l + 1 : l;  // next-layer param prefetch
        float nbo = bo[(size_t)ln * DD + d];
        float nlw = lnw[(size_t)ln * DD + d];
        float nlb = lnb[(size_t)ln * DD + d];
        float nbf = bff[(size_t)ln * DD + d];

        float xp0 = h0v + pbo;
        float xp1 = h1v + pbo;
        // one-pass LN stats, 4 interleaved shfl chains
        float s0 = xp0, q0 = xp0 * xp0;
        float s1 = xp1, q1 = xp1 * xp1;
#pragma unroll
        for (int o = 32; o; o >>= 1) {
            s0 += __shfl_down(s0, o, 64);
            q0 += __shfl_down(q0, o, 64);
            s1 += __shfl_down(s1, o, 64);
            q1 += __shfl_down(q1, o, 64);
        }
        if (lane == 0) {
            red[r0][wv]     = make_float2(s0, q0);
            red[r0 + 1][wv] = make_float2(s1, q1);
        }
        __syncthreads();                    // B1
        {
            float4 A = ((const float4*)&red[r0][0])[0], B = ((const float4*)&red[r0][0])[1];
            float mu = (A.x + A.z + B.x + B.z) * (1.0f / 256.0f);
            float ms = (A.y + A.w + B.y + B.w) * (1.0f / 256.0f);
            float var = ms - mu * mu; var = var < 0.f ? 0.f : var;
            float inv = 1.0f / sqrtf(var + 1e-5f);
            ((float*)shnT)[d * 8 + r0] = (xp0 - mu) * inv * plw + plb;
        }
        {
            float4 A = ((const float4*)&red[r0+1][0])[0], B = ((const float4*)&red[r0+1][0])[1];
            float mu = (A.x + A.z + B.x + B.z) * (1.0f / 256.0f);
            float ms = (A.y + A.w + B.y + B.w) * (1.0f / 256.0f);
            float var = ms - mu * mu; var = var < 0.f ? 0.f : var;
            float inv = 1.0f / sqrtf(var + 1e-5f);
            ((float*)shnT)[d * 8 + r0 + 1] = (xp1 - mu) * inv * plw + plb;
        }
        __syncthreads();                    // B2

        // FF: k in [m*32, m*32+32), cols {2cg, 2cg+1}; 8-deep b64 W prefetch
        float2 acc[BM];
#pragma unroll
        for (int r = 0; r < BM; r++) acc[r] = make_float2(0.f, 0.f);
        {
            const float2* Wp = (const float2*)(Wff + (size_t)l * DD * DD) + cg;
            const int kb = m * 32;
            float2 wA[8], wB[8];
#pragma unroll
            for (int t = 0; t < 8; t++) wA[t] = Wp[(size_t)(kb + t) * 128];
#pragma unroll
            for (int g = 0; g < 4; g++) {
                if (g < 3) {
#pragma unroll
                    for (int t = 0; t < 8; t++) wB[t] = Wp[(size_t)(kb + g * 8 + 8 + t) * 128];
                }
#pragma unroll
                for (int t = 0; t < 8; t++) {
                    int k = kb + g * 8 + t;
                    float4 sa = shnT[k][0], sb = shnT[k][1];   // uniform-addr b128 broadcast
                    float2 w2 = wA[t];
                    acc[0].x = fmaf(sa.x, w2.x, acc[0].x); acc[0].y = fmaf(sa.x, w2.y, acc[0].y);
                    acc[1].x = fmaf(sa.y, w2.x, acc[1].x); acc[1].y = fmaf(sa.y, w2.y, acc[1].y);
                    acc[2].x = fmaf(sa.z, w2.x, acc[2].x); acc[2].y = fmaf(sa.z, w2.y, acc[2].y);
                    acc[3].x = fmaf(sa.w, w2.x, acc[3].x); acc[3].y = fmaf(sa.w, w2.y, acc[3].y);
                    acc[4].x = fmaf(sb.x, w2.x, acc[4].x); acc[4].y = fmaf(sb.x, w2.y, acc[4].y);
                    acc[5].x = fmaf(sb.y, w2.x, acc[5].x); acc[5].y = fmaf(sb.y, w2.y, acc[5].y);
                    acc[6].x = fmaf(sb.z, w2.x, acc[6].x); acc[6].y = fmaf(sb.z, w2.y, acc[6].y);
                    acc[7].x = fmaf(sb.w, w2.x, acc[7].x); acc[7].y = fmaf(sb.w, w2.y, acc[7].y);
                }
                if (g < 3) {
#pragma unroll
                    for (int t = 0; t < 8; t++) wA[t] = wB[t];
                }
            }
        }
        if (wid < 8) {
#pragma unroll
            for (int r = 0; r < BM; r++) *(float2*)&part[m][r][2 * cg] = acc[r];
        }
        __syncthreads();                    // B3
        if (wid >= 8) {
#pragma unroll
            for (int r = 0; r < BM; r++) {
                float2 p = *(float2*)&part[m - 4][r][2 * cg];
                p.x += acc[r].x; p.y += acc[r].y;
                *(float2*)&part[m - 4][r][2 * cg] = p;
            }
        }
        __syncthreads();                    // B4
        h0v = part[0][r0][d] + part[1][r0][d] + part[2][r0][d] + part[3][r0][d] + pbf + xp0;
        h1v = part[0][r0+1][d] + part[1][r0+1][d] + part[2][r0+1][d] + part[3][r0+1][d] + pbf + xp1;
        pbo = nbo; plw = nlw; plb = nlb; pbf = nbf;
        // hazards: red r@B1-B2 w@preB1' (sep B2..B4); shnT w@B1-B2 r@B2-B3
        // next-w after B4+B1'; part w@preB3/B3-B4 r@postB4, next-w after B1',B2'.
    }

    // ---- out = h@Wout + b_out: 4-row b128 broadcasts, 8-way k-split ----
    ((float*)shnT)[d * 8 + r0]     = h0v;   // shnT last read pre-B3 of final layer
    ((float*)shnT)[d * 8 + r0 + 1] = h1v;
    __syncthreads();                        // Be1 (covers part reads above + shnT writes)
    {
        const int s  = wid >> 1;            // k-chunk 0..7 (32 wide)
        const int r4 = wid & 1;             // row group: rows r4*4 .. r4*4+3
        const int e  = lane;
        const float* Wo = Wout + e;
        const int kb = s * 32;
        float wA[8], wB[8];
#pragma unroll
        for (int t = 0; t < 8; t++) wA[t] = Wo[(size_t)(kb + t) * DOUT];
        float a0 = 0.f, a1 = 0.f, a2 = 0.f, a3 = 0.f;
#pragma unroll
        for (int g = 0; g < 4; g++) {
            if (g < 3) {
#pragma unroll
                for (int t = 0; t < 8; t++) wB[t] = Wo[(size_t)(kb + g * 8 + 8 + t) * DOUT];
            }
#pragma unroll
            for (int t = 0; t < 8; t++) {
                float4 sv = shnT[kb + g * 8 + t][r4];   // uniform-addr b128
                float w = wA[t];
                a0 = fmaf(sv.x, w, a0); a1 = fmaf(sv.y, w, a1);
                a2 = fmaf(sv.z, w, a2); a3 = fmaf(sv.w, w, a3);
            }
            if (g < 3) {
#pragma unroll
                for (int t = 0; t < 8; t++) wA[t] = wB[t];
            }
        }
        float* pf = (float*)part;           // po[s][r][e] : 8*8*64 = 16 KB
        const int rb = r4 * 4;
        pf[s * 512 + (rb + 0) * 64 + e] = a0;
        pf[s * 512 + (rb + 1) * 64 + e] = a1;
        pf[s * 512 + (rb + 2) * 64 + e] = a2;
        pf[s * 512 + (rb + 3) * 64 + e] = a3;
    }
    __syncthreads();                        // Be2
    if (tid < BM * DOUT) {
        int r = tid >> 6, e = tid & 63;
        const float* pf = (const float*)part;
        float o = bout[e];
#pragma unroll
        for (int s = 0; s < 8; s++) o += pf[s * 512 + r * 64 + e];
        out[(size_t)(n0 + r) * DOUT + e] = o;
    }
}

// ---------------- host ----------------

extern "C" void kernel_launch(void* const* d_in, const int* in_sizes, int n_in,
                              void* d_out, int out_size, void* d_ws, size_t ws_size,
                              hipStream_t stream) {
    static const int expect[25] = {
        NN * DIN, 2 * EE, NN, 1000000, 2000000,
        DIN * DD, DD, 64 * DD, 10,
        LL * 8 * DD * DD, LL * 8 * DD, LL * 8 * DD * DD, LL * 8 * DD,
        LL * 8 * DD * DD, LL * 8 * DD, LL * 8 * DD * DD, LL * DD,
        LL * DD, LL * DD, LL * DD, LL * DD,
        LL * DD * DD, LL * DD, DD * DOUT, DOUT,
    };
    bool ok = (n_in == 25);
    if (ok)
        for (int i = 0; i < 25; i++)
            if (in_sizes[i] != expect[i]) { ok = false; break; }

    int* deg = (int*)d_ws;  // 8 KB
    if (!ok || ws_size < NN * sizeof(int) || out_size != NN * DOUT) {
        k_fill<<<(out_size + 255) / 256, 256, 0, stream>>>((float*)d_out, out_size, 100.0f);
        return;
    }

    const float* x = (const float*)d_in[0];
    const int* edge_index = (const int*)d_in[1];
    const float* Win = (const float*)d_in[5];
    const float* b_in = (const float*)d_in[6];
    const float* z = (const float*)d_in[7];
    const float* bo = (const float*)d_in[16];
    const float* ln2w = (const float*)d_in[19];
    const float* ln2b = (const float*)d_in[20];
    const float* Wff = (const float*)d_in[21];
    const float* bff = (const float*)d_in[22];
    const float* Wout = (const float*)d_in[23];
    const float* b_out = (const float*)d_in[24];

    hipMemsetAsync(deg, 0, NN * sizeof(int), stream);
    k_deg<<<8, 1024, 0, stream>>>(edge_index, deg);
    k_mega<<<NN / BM, 1024, 0, stream>>>(x, deg, Win, b_in, z, bo, ln2w, ln2b,
                                         Wff, bff, Wout, b_out, (float*)d_out);
}